// Round 16
// baseline (77.642 us; speedup 1.0000x reference)
//
#include <hip/hip_runtime.h>
#include <hip/hip_fp16.h>
#include <math.h>
#include <stdint.h>

#define U 50
#define TT 100
#define BB 256

typedef _Float16 half2v __attribute__((ext_vector_type(2)));

__device__ __forceinline__ float dot2_acc(uint32_t h2, uint32_t w2, float c) {
#if __has_builtin(__builtin_amdgcn_fdot2)
    return __builtin_amdgcn_fdot2(__builtin_bit_cast(half2v, h2),
                                  __builtin_bit_cast(half2v, w2), c, false);
#else
    half2v a = __builtin_bit_cast(half2v, h2);
    half2v b = __builtin_bit_cast(half2v, w2);
    return fmaf((float)a.x, (float)b.x, fmaf((float)a.y, (float)b.y, c));
#endif
}

__device__ __forceinline__ float sigmoid_fast(float x) {
    return 1.0f / (1.0f + __expf(-x));   // saturates cleanly, no NaN
}
__device__ __forceinline__ float tanh_fast(float x) {
    float e = __expf(2.0f * x);
    return 1.0f - 2.0f / (e + 1.0f);     // saturates cleanly, no NaN
}
__device__ __forceinline__ float param_act(float x, float mn, float mx) {
    float scale = 0.5f * (mx - mn);
    return tanh_fast(x) * scale + mn + scale;
}

// lgkm-only barrier (round-14): no vmcnt drain in the loop.
#define BAR() do {                                            \
    asm volatile("s_waitcnt lgkmcnt(0)" ::: "memory");        \
    __builtin_amdgcn_s_barrier();                             \
    asm volatile("" ::: "memory");                            \
} while (0)

// TWO batches per block (ILP): wave w owns gate w of unit l for BOTH batches.
// The weight registers (wpk, kc, bz) depend only on (gate,unit) -> shared by
// the two batches; only hvu/cstate duplicate. The two independent dependency
// chains interleave instruction-by-instruction, hiding each other's LDS/dep
// latency (round-14 lesson: the step was ~75% serial stall at 1 wave/SIMD).
__global__ __launch_bounds__(256, 1) void encoder_kernel(
    const float* __restrict__ x,        // (B,T,4)
    const float* __restrict__ state,    // (B,T,4)
    const float* __restrict__ kernel,   // (4,200)
    const float* __restrict__ rec,      // (50,200)
    const float* __restrict__ bias,     // (200,)
    const float* __restrict__ w_dv, const float* __restrict__ b_dv,
    const float* __restrict__ w_dt, const float* __restrict__ b_dt,
    const float* __restrict__ w_mj, const float* __restrict__ b_mj,
    const float* __restrict__ w_ma, const float* __restrict__ b_ma,
    const float* __restrict__ w_mi, const float* __restrict__ b_mi,
    float* __restrict__ out)            // act_seq (B*T) then idm (B*5)
{
    const int bg0 = blockIdx.x * 2;     // batches bg0, bg0+1
    const int tid = threadIdx.x;
    const int w   = tid >> 6;           // gate owned by this wave (0..3)
    const int l   = tid & 63;
    const int cl  = (l < U) ? l : (U - 1);

    __shared__ __align__(16) float4 xlds[2][TT];     // staged x, both batches
    __shared__ __align__(16) _Float16 h16[2][64];    // h state (f16)
    __shared__ float zex[2][2][4][64];               // [batch][dbuf][gate][l]
    __shared__ float idm[2][8];

    // ---- per-lane weights: gate w, column cl -- shared by both batches ----
    uint32_t wpk[25];
    #pragma unroll
    for (int j = 0; j < 25; ++j) {
        float r0 = rec[(2 * j) * 200 + w * U + cl];
        float r1 = rec[(2 * j + 1) * 200 + w * U + cl];
        half2v p; p.x = (_Float16)r0; p.y = (_Float16)r1;
        wpk[j] = __builtin_bit_cast(uint32_t, p);
    }
    #pragma unroll
    for (int j = 0; j < 25; ++j) asm volatile("" : "+v"(wpk[j]));

    float kc[4];
    #pragma unroll
    for (int f = 0; f < 4; ++f) kc[f] = kernel[f * 200 + w * U + cl];
    float bz = bias[w * U + cl];

    // ---- stage x for both batches, init h ----
    const float4* __restrict__ xg0 = (const float4*)(x + (size_t)bg0 * TT * 4);
    const float4* __restrict__ xg1 = (const float4*)(x + (size_t)(bg0 + 1) * TT * 4);
    if (tid < TT) xlds[0][tid] = xg0[tid];
    else if (tid < 2 * TT) xlds[1][tid - TT] = xg1[tid - TT];
    if (tid < 64) { h16[0][tid] = (_Float16)0.0f; h16[1][tid] = (_Float16)0.0f; }
    __syncthreads();

    float cA = 0.0f, cB = 0.0f;
    uint32_t hva[25], hvb[25];
    #pragma unroll
    for (int j = 0; j < 25; ++j) { hva[j] = 0u; hvb[j] = 0u; }

    const uint4* __restrict__ hqA = (const uint4*)&h16[0][0];
    const uint4* __restrict__ hqB = (const uint4*)&h16[1][0];
    const uint32_t* __restrict__ hdA = (const uint32_t*)&h16[0][0];
    const uint32_t* __restrict__ hdB = (const uint32_t*)&h16[1][0];

    for (int t = 0; t < TT; ++t) {
        float4 xa = xlds[0][t];
        float4 xb = xlds[1][t];

        float zA = fmaf(xa.x, kc[0], fmaf(xa.y, kc[1],
                   fmaf(xa.z, kc[2], fmaf(xa.w, kc[3], bz))));
        float zB = fmaf(xb.x, kc[0], fmaf(xb.y, kc[1],
                   fmaf(xb.z, kc[2], fmaf(xb.w, kc[3], bz))));

        // interleaved dot2: 2 chains per batch, batches alternate
        float a0 = 0.f, a1 = 0.f, b0 = 0.f, b1 = 0.f;
        #pragma unroll
        for (int j = 0; j < 24; j += 2) {
            a0 = dot2_acc(hva[j],     wpk[j],     a0);
            b0 = dot2_acc(hvb[j],     wpk[j],     b0);
            a1 = dot2_acc(hva[j + 1], wpk[j + 1], a1);
            b1 = dot2_acc(hvb[j + 1], wpk[j + 1], b1);
        }
        a0 = dot2_acc(hva[24], wpk[24], a0);
        b0 = dot2_acc(hvb[24], wpk[24], b0);
        zA += a0 + a1;
        zB += b0 + b1;

        // own gate's nonlinearity, both batches (exps in parallel across waves)
        float nlA = (w == 2) ? tanh_fast(zA) : sigmoid_fast(zA);
        float nlB = (w == 2) ? tanh_fast(zB) : sigmoid_fast(zB);
        const int buf = t & 1;
        zex[0][buf][w][l] = nlA;             // stride-4B: conflict-free
        zex[1][buf][w][l] = nlB;

        BAR();                               // lgkm-only: zex(t) visible

        // redundant c/h chain on ALL waves, both batches interleaved
        float giA = zex[0][buf][0][l], gfA = zex[0][buf][1][l];
        float ggA = zex[0][buf][2][l], goA = zex[0][buf][3][l];
        float giB = zex[1][buf][0][l], gfB = zex[1][buf][1][l];
        float ggB = zex[1][buf][2][l], goB = zex[1][buf][3][l];
        cA = fmaf(gfA, cA, giA * ggA);
        cB = fmaf(gfB, cB, giB * ggB);
        float hnA = goA * tanh_fast(cA);
        float hnB = goB * tanh_fast(cB);
        if (l < U) h16[0][l] = (_Float16)hnA;   // 4x same-value: benign
        if (l < U) h16[1][l] = (_Float16)hnB;

        // reload packed h(t+1) for both batches (own-wave order via lgkmcnt)
        #pragma unroll
        for (int q = 0; q < 6; ++q) {
            uint4 vA = hqA[q];
            uint4 vB = hqB[q];
            hva[4 * q + 0] = vA.x; hva[4 * q + 1] = vA.y;
            hva[4 * q + 2] = vA.z; hva[4 * q + 3] = vA.w;
            hvb[4 * q + 0] = vB.x; hvb[4 * q + 1] = vB.y;
            hvb[4 * q + 2] = vB.z; hvb[4 * q + 3] = vB.w;
        }
        hva[24] = hdA[24];
        hvb[24] = hdB[24];
    }

    // ---- 5 heads x 2 batches (threads 0..9, wave 0 wrote h16 itself) ----
    if (tid < 10) {
        const int bi = tid / 5, head = tid % 5;
        const float* wv = (head == 0) ? w_dv : (head == 1) ? w_dt :
                          (head == 2) ? w_mj : (head == 3) ? w_ma : w_mi;
        const float* bv = (head == 0) ? b_dv : (head == 1) ? b_dt :
                          (head == 2) ? b_mj : (head == 3) ? b_ma : b_mi;
        float s = bv[0];
        #pragma unroll
        for (int j = 0; j < U; ++j) s = fmaf((float)h16[bi][j], wv[j], s);
        float v;
        if (head == 0)      v = param_act(s, 15.0f, 35.0f);
        else if (head == 1) v = param_act(s, 0.5f, 3.0f);
        else if (head == 2) v = fmaxf(s, 0.0f);
        else if (head == 3) v = param_act(s, 0.5f, 3.0f);
        else                v = param_act(s, 0.5f, 4.0f);
        idm[bi][head] = v;
        out[BB * TT + (bg0 + bi) * 5 + head] = v;
    }
    __syncthreads();

    // ---- IDM physics: 200 outputs over 256 threads, single pass ----
    if (tid < 2 * TT) {
        const int bi = tid / TT, t = tid % TT;
        const int bg = bg0 + bi;
        const float desired_v    = idm[bi][0];
        const float desired_tgap = idm[bi][1];
        const float min_jamx     = idm[bi][2];
        const float max_act      = idm[bi][3];
        const float min_act      = idm[bi][4];
        const float inv_tsab = 1.0f / (2.0f * sqrtf(max_act * min_act));
        const float inv_dv   = 1.0f / desired_v;
        float4 s4 = ((const float4*)(state + (size_t)bg * TT * 4))[t];
        float vel = s4.x, dv = s4.z, dx = s4.w;
        float dgap = fmaf(desired_tgap, vel, fmaf(vel * dv, inv_tsab, min_jamx));
        float r1 = vel * inv_dv;
        r1 = r1 * r1; r1 = r1 * r1;   // ^4
        float r2 = dgap / dx;
        r2 = r2 * r2;                 // ^2
        out[bg * TT + t] = max_act * (1.0f - (r1 + r2));
    }
}

extern "C" void kernel_launch(void* const* d_in, const int* in_sizes, int n_in,
                              void* d_out, int out_size, void* d_ws, size_t ws_size,
                              hipStream_t stream) {
    const float* x      = (const float*)d_in[0];
    const float* state  = (const float*)d_in[1];
    const float* kern   = (const float*)d_in[2];
    const float* rec    = (const float*)d_in[3];
    const float* bias   = (const float*)d_in[4];
    const float* w_dv   = (const float*)d_in[5];
    const float* b_dv   = (const float*)d_in[6];
    const float* w_dt   = (const float*)d_in[7];
    const float* b_dt   = (const float*)d_in[8];
    const float* w_mj   = (const float*)d_in[9];
    const float* b_mj   = (const float*)d_in[10];
    const float* w_ma   = (const float*)d_in[11];
    const float* b_ma   = (const float*)d_in[12];
    const float* w_mi   = (const float*)d_in[13];
    const float* b_mi   = (const float*)d_in[14];
    float* out = (float*)d_out;

    encoder_kernel<<<BB / 2, 256, 0, stream>>>(
        x, state, kern, rec, bias,
        w_dv, b_dv, w_dt, b_dt, w_mj, b_mj, w_ma, b_ma, w_mi, b_mi,
        out);
}

// Round 17
// 57.707 us; speedup vs baseline: 1.3455x; 1.3455x over previous
//
#include <hip/hip_runtime.h>
#include <hip/hip_fp16.h>
#include <math.h>
#include <stdint.h>

#define U 50
#define TT 100
#define BB 256

typedef _Float16 half2v __attribute__((ext_vector_type(2)));

__device__ __forceinline__ float dot2_acc(uint32_t h2, uint32_t w2, float c) {
#if __has_builtin(__builtin_amdgcn_fdot2)
    return __builtin_amdgcn_fdot2(__builtin_bit_cast(half2v, h2),
                                  __builtin_bit_cast(half2v, w2), c, false);
#else
    half2v a = __builtin_bit_cast(half2v, h2);
    half2v b = __builtin_bit_cast(half2v, w2);
    return fmaf((float)a.x, (float)b.x, fmaf((float)a.y, (float)b.y, c));
#endif
}

__device__ __forceinline__ float sigmoid_fast(float x) {
    return 1.0f / (1.0f + __expf(-x));   // saturates cleanly, no NaN
}
__device__ __forceinline__ float tanh_fast(float x) {
    float e = __expf(2.0f * x);
    return 1.0f - 2.0f / (e + 1.0f);     // saturates cleanly, no NaN
}
__device__ __forceinline__ float param_act(float x, float mn, float mx) {
    float scale = 0.5f * (mx - mn);
    return tanh_fast(x) * scale + mn + scale;
}

// In-register quad butterfly sum (lanes 4i..4i+3): DPP quad_perm [1,0,3,2]
// then [2,3,0,1] -- pure VALU, no LDS, no barrier.
__device__ __forceinline__ float quad_sum(float v) {
    int a = __builtin_amdgcn_mov_dpp(__builtin_bit_cast(int, v), 0xB1, 0xF, 0xF, true);
    float s = v + __builtin_bit_cast(float, a);
    int b = __builtin_amdgcn_mov_dpp(__builtin_bit_cast(int, s), 0x4E, 0xF, 0xF, true);
    return s + __builtin_bit_cast(float, b);
}

// lgkm-only barrier (round-14): no vmcnt drain in the loop.
#define BAR() do {                                            \
    asm volatile("s_waitcnt lgkmcnt(0)" ::: "memory");        \
    __builtin_amdgcn_s_barrier();                             \
    asm volatile("" ::: "memory");                            \
} while (0)

// Extended-vector weight element: h~ = [h(50) | x(4) | 1 | 0...] (K=64),
// W~[j][g,u] = rec / kernel / bias / 0.
__device__ __forceinline__ float welem(const float* __restrict__ rec,
                                       const float* __restrict__ kern,
                                       const float* __restrict__ bias,
                                       int unit, int g, int j) {
    if (unit >= U) return 0.0f;
    if (j < U)      return rec[j * 200 + g * U + unit];
    if (j < U + 4)  return kern[(j - U) * 200 + g * U + unit];
    if (j == U + 4) return bias[g * U + unit];
    return 0.0f;
}

// One batch per block, 4 waves. Lane = 4*u_local + kq: wave w owns units
// 16w..16w+15; lane (u,kq) computes ALL 4 gates over k-quarter kq (8 packed
// pairs = 32 weight dwords/lane, bias+x folded into the dot). Gate reduction
// is a DPP quad butterfly (no LDS); c/h computed redundantly per quad; kq==0
// writes h. h~ is double-buffered -> ONE lgkm-only barrier and ONE LDS round
// trip per step (round 14 had two round trips).
__global__ __launch_bounds__(256, 1) void encoder_kernel(
    const float* __restrict__ x,        // (B,T,4)
    const float* __restrict__ state,    // (B,T,4)
    const float* __restrict__ kernel,   // (4,200)
    const float* __restrict__ rec,      // (50,200)
    const float* __restrict__ bias,     // (200,)
    const float* __restrict__ w_dv, const float* __restrict__ b_dv,
    const float* __restrict__ w_dt, const float* __restrict__ b_dt,
    const float* __restrict__ w_mj, const float* __restrict__ b_mj,
    const float* __restrict__ w_ma, const float* __restrict__ b_ma,
    const float* __restrict__ w_mi, const float* __restrict__ b_mi,
    float* __restrict__ out)            // act_seq (B*T) then idm (B*5)
{
    const int b   = blockIdx.x;
    const int tid = threadIdx.x;
    const int w   = tid >> 6;
    const int l   = tid & 63;
    const int kq  = l & 3;              // k-quarter 0..3 (16 elems each)
    const int ul  = l >> 2;             // unit-in-wave 0..15
    const int unit = 16 * w + ul;       // active if < 50

    __shared__ __align__(16) float4 xlds[TT];        // staged x(b,:,:)
    __shared__ __align__(16) _Float16 hbuf[2][64];   // dbuf h~ = [h|x|1|0]
    __shared__ float idm[8];

    // ---- per-lane weights: 4 gates x 8 pairs of the extended column ----
    uint32_t wpk[4][8];
    #pragma unroll
    for (int g = 0; g < 4; ++g) {
        #pragma unroll
        for (int p = 0; p < 8; ++p) {
            const int jj = 2 * (8 * kq + p);
            float f0 = welem(rec, kernel, bias, unit, g, jj);
            float f1 = welem(rec, kernel, bias, unit, g, jj + 1);
            half2v pk; pk.x = (_Float16)f0; pk.y = (_Float16)f1;
            wpk[g][p] = __builtin_bit_cast(uint32_t, pk);
        }
    }
    #pragma unroll
    for (int g = 0; g < 4; ++g)
        #pragma unroll
        for (int p = 0; p < 8; ++p) asm volatile("" : "+v"(wpk[g][p]));

    // ---- stage x; init both h~ buffers ----
    if (tid < TT) xlds[tid] = ((const float4*)(x + (size_t)b * TT * 4))[tid];
    if (tid < 64) {
        _Float16 v0 = (_Float16)0.0f, v1 = (_Float16)0.0f;
        if (tid >= U && tid < U + 4)
            v0 = (_Float16)x[(size_t)b * TT * 4 + (tid - U)];   // x(0)
        if (tid == U + 4) { v0 = (_Float16)1.0f; v1 = (_Float16)1.0f; }
        hbuf[0][tid] = v0;
        hbuf[1][tid] = v1;
    }
    __syncthreads();

    float cstate = 0.0f;
    float hT = 0.0f;

    for (int t = 0; t < TT; ++t) {
        const int rb = t & 1, wb = rb ^ 1;

        // own k-quarter of h~(t): 2x ds_read_b128 (quad-broadcast)
        const uint4* hb = (const uint4*)&hbuf[rb][0];
        uint4 q0 = hb[2 * kq + 0];
        uint4 q1 = hb[2 * kq + 1];
        uint32_t hv[8] = {q0.x, q0.y, q0.z, q0.w, q1.x, q1.y, q1.z, q1.w};

        // x(t+1) for staging (single lane; independent LDS read)
        float4 xn = {0.f, 0.f, 0.f, 0.f};
        if (tid == 0) xn = xlds[(t + 1 < TT) ? (t + 1) : t];

        // 32 dot2: 4 gates x 2 chains x depth 4
        float za[4] = {0.f, 0.f, 0.f, 0.f};
        float zb[4] = {0.f, 0.f, 0.f, 0.f};
        #pragma unroll
        for (int p = 0; p < 8; p += 2) {
            #pragma unroll
            for (int g = 0; g < 4; ++g) {
                za[g] = dot2_acc(hv[p],     wpk[g][p],     za[g]);
                zb[g] = dot2_acc(hv[p + 1], wpk[g][p + 1], zb[g]);
            }
        }

        // quad butterfly: full z in every lane (DPP, no LDS)
        float z0 = quad_sum(za[0] + zb[0]);
        float z1 = quad_sum(za[1] + zb[1]);
        float z2 = quad_sum(za[2] + zb[2]);
        float z3 = quad_sum(za[3] + zb[3]);

        // redundant (per-quad) gate math
        float gi = sigmoid_fast(z0);
        float gf = sigmoid_fast(z1);
        float gg = tanh_fast(z2);
        float go = sigmoid_fast(z3);
        cstate = fmaf(gf, cstate, gi * gg);
        float hn = go * tanh_fast(cstate);
        hT = hn;
        if (kq == 0 && unit < U) hbuf[wb][unit] = (_Float16)hn;
        if (tid == 0) {
            half2v p0; p0.x = (_Float16)xn.x; p0.y = (_Float16)xn.y;
            half2v p1; p1.x = (_Float16)xn.z; p1.y = (_Float16)xn.w;
            *(uint32_t*)&hbuf[wb][U]     = __builtin_bit_cast(uint32_t, p0);
            *(uint32_t*)&hbuf[wb][U + 2] = __builtin_bit_cast(uint32_t, p1);
        }

        BAR();   // h~(t+1) complete & visible; buffers swap
    }
    (void)hT;

    // ---- 5 output heads (h(T) is in hbuf[0]; TT even) ----
    if (tid < 5) {
        const float* wv = (tid == 0) ? w_dv : (tid == 1) ? w_dt :
                          (tid == 2) ? w_mj : (tid == 3) ? w_ma : w_mi;
        const float* bv = (tid == 0) ? b_dv : (tid == 1) ? b_dt :
                          (tid == 2) ? b_mj : (tid == 3) ? b_ma : b_mi;
        float s = bv[0];
        #pragma unroll
        for (int j = 0; j < U; ++j) s = fmaf((float)hbuf[0][j], wv[j], s);
        float v;
        if (tid == 0)      v = param_act(s, 15.0f, 35.0f);
        else if (tid == 1) v = param_act(s, 0.5f, 3.0f);
        else if (tid == 2) v = fmaxf(s, 0.0f);
        else if (tid == 3) v = param_act(s, 0.5f, 3.0f);
        else               v = param_act(s, 0.5f, 4.0f);
        idm[tid] = v;
        out[BB * TT + b * 5 + tid] = v;
    }
    __syncthreads();

    // ---- IDM physics over T (single pass, threads 0..99) ----
    if (tid < TT) {
        const float desired_v    = idm[0];
        const float desired_tgap = idm[1];
        const float min_jamx     = idm[2];
        const float max_act      = idm[3];
        const float min_act      = idm[4];
        const float inv_tsab = 1.0f / (2.0f * sqrtf(max_act * min_act));
        const float inv_dv   = 1.0f / desired_v;
        float4 s4 = ((const float4*)(state + (size_t)b * TT * 4))[tid];
        float vel = s4.x, dv = s4.z, dx = s4.w;
        float dgap = fmaf(desired_tgap, vel, fmaf(vel * dv, inv_tsab, min_jamx));
        float r1 = vel * inv_dv;
        r1 = r1 * r1; r1 = r1 * r1;   // ^4
        float r2 = dgap / dx;
        r2 = r2 * r2;                 // ^2
        out[b * TT + tid] = max_act * (1.0f - (r1 + r2));
    }
}

extern "C" void kernel_launch(void* const* d_in, const int* in_sizes, int n_in,
                              void* d_out, int out_size, void* d_ws, size_t ws_size,
                              hipStream_t stream) {
    const float* x      = (const float*)d_in[0];
    const float* state  = (const float*)d_in[1];
    const float* kern   = (const float*)d_in[2];
    const float* rec    = (const float*)d_in[3];
    const float* bias   = (const float*)d_in[4];
    const float* w_dv   = (const float*)d_in[5];
    const float* b_dv   = (const float*)d_in[6];
    const float* w_dt   = (const float*)d_in[7];
    const float* b_dt   = (const float*)d_in[8];
    const float* w_mj   = (const float*)d_in[9];
    const float* b_mj   = (const float*)d_in[10];
    const float* w_ma   = (const float*)d_in[11];
    const float* b_ma   = (const float*)d_in[12];
    const float* w_mi   = (const float*)d_in[13];
    const float* b_mi   = (const float*)d_in[14];
    float* out = (float*)d_out;

    encoder_kernel<<<BB, 256, 0, stream>>>(
        x, state, kern, rec, bias,
        w_dv, b_dv, w_dt, b_dt, w_mj, b_mj, w_ma, b_ma, w_mi, b_mi,
        out);
}